// Round 14
// baseline (157.116 us; speedup 1.0000x reference)
//
#include <hip/hip_runtime.h>

// Flash attention fwd. q[B,N,D], k[B,D,N] (=K^T), v[B,N,D] fp32 in, fp32 out.
// B=16, N=2048, D=128. fp16 MFMA (32x32x16), fp32 accumulate.
// R20 (2 independent blocks/CU; R13 geometry with the spill removed):
//  - All single-block structures pinned at ~67-70us across R9-R19; refuted
//    theories: vmcnt drain (R16), bank conflicts (R17), DS instr count
//    (R19). Remaining: per-wave latency chains + barrier convoy with no
//    independent-phase partner on the SIMD. Fix: 256-thr blocks (2
//    consumer waves BM=64 + 2 producer waves), grid 512 = 2 blocks/CU
//    with DECOUPLED barriers -- block A stalls, block B issues.
//  - R13 tried this and spilled (double 16-float4 staging = 128 regs ->
//    WRITE_SIZE 183MB). Here: SINGLE 8-float4 staging set per producer
//    thread, write-then-reissue (R14's proven pattern): write_lds(t+1)
//    waits on loads issued one interval ago, then reissues for t+2.
//  - Consumer = R19 body minus the accT split chain (neutral, -32 regs).
//    Staging layout byte-identical to R19 (b64 writes, same swizzles).
//  - P^T in regs, exp2 softmax, defer-rescale THR=8, setprio, XCD swizzle.

typedef __attribute__((ext_vector_type(8))) _Float16 f16x8;
typedef __attribute__((ext_vector_type(16))) float f32x16;
typedef __attribute__((ext_vector_type(2))) uint u32x2;

constexpr int Bz = 16;
constexpr int Nn = 2048;
constexpr int Dd = 128;
constexpr int BM = 64;   // q rows per block (2 consumer waves x 32)
constexpr int BN = 32;   // keys per iteration

__device__ __forceinline__ int swz(int r) { return (r ^ (r >> 3)) & 7; }
__device__ __forceinline__ int sw4(int d) { return ((d >> 1) ^ (d >> 3)) & 3; }

__device__ __forceinline__ uint pkrtz(float a, float b) {
    return __builtin_bit_cast(uint, __builtin_amdgcn_cvt_pkrtz(a, b));
}

__device__ __forceinline__ float exp2i(float x) {
    return __builtin_amdgcn_exp2f(x);   // raw v_exp_f32 (2^x)
}

__global__ __launch_bounds__(256, 2)
void fattn_kernel(const float* __restrict__ qg,
                  const float* __restrict__ kg,
                  const float* __restrict__ vg,
                  float* __restrict__ og)
{
    __shared__ ushort lds_k[2][BN * Dd];   // [kk][d ^ swizzle]  2 x 8 KB
    __shared__ ushort lds_v[2][Dd * BN];   // [d'][kk ^ swizzle] 2 x 8 KB

    const int bid  = blockIdx.x;           // 512 blocks
    const int xcd  = bid & 7;
    const int idx  = bid >> 3;             // 0..63
    const int b    = xcd * 2 + (idx >> 5); // 2 batches per XCD (K/V fits L2)
    const int q0   = (idx & 31) * BM;
    const int tid  = threadIdx.x;
    const int wv   = tid >> 6;             // 0..3
    const int lane = tid & 63;
    const int h    = lane >> 5;            // half-wave (k-slice)
    const int l31  = lane & 31;
    const bool producer = (wv >= 2);

    // ================= producer state =================
    const int ptid = (wv - 2) * 64 + lane;     // 0..127 (producers only)
    const int k8 = ptid >> 3;     // K: d-octet 0..15 (8 d-rows)
    const int kc = ptid & 7;      // K: n-quad (4 n's)
    const int v4 = ptid >> 5;     // V: kk-octet 0..3 (8 kk-rows)
    const int vc = ptid & 31;     // V: d-quad (4 d's)
    const float* kbase = kg + (size_t)b * Dd * Nn;
    const float* vbase = vg + (size_t)b * Nn * Dd;
    float4 kr[8], vr[8];   // SINGLE staging set (write tile t+1, then reissue t+2)

    auto issue_loads = [&](int n0) {
        const float* s0 = kbase + (size_t)(k8 * 8) * Nn + n0 + kc * 4;
        #pragma unroll
        for (int j = 0; j < 8; ++j) kr[j] = *(const float4*)(s0 + (size_t)j * Nn);
        const float* t0 = vbase + (size_t)(n0 + v4 * 8) * Dd + vc * 4;
        #pragma unroll
        for (int j = 0; j < 8; ++j) vr[j] = *(const float4*)(t0 + (size_t)j * Dd);
    };
    auto write_lds = [&](int buf) {
        // K: uint2 idx = n*32 + (dquad ^ (swz(n)<<1) ^ (n&8))  (== R19 layout)
        u32x2* kw2 = (u32x2*)lds_k[buf];
        #pragma unroll
        for (int j = 0; j < 4; ++j) {
            const int n = kc * 4 + j;
            const int sx = (swz(n) << 1) ^ (n & 8);
            u32x2 p0, p1;
            p0[0] = pkrtz(((const float*)&kr[0])[j], ((const float*)&kr[1])[j]);
            p0[1] = pkrtz(((const float*)&kr[2])[j], ((const float*)&kr[3])[j]);
            p1[0] = pkrtz(((const float*)&kr[4])[j], ((const float*)&kr[5])[j]);
            p1[1] = pkrtz(((const float*)&kr[6])[j], ((const float*)&kr[7])[j]);
            kw2[n * 32 + ((2 * k8)     ^ sx)] = p0;   // d 8k8..8k8+3
            kw2[n * 32 + ((2 * k8 + 1) ^ sx)] = p1;   // d 8k8+4..8k8+7
        }
        // V: uint2 idx = rowp*8 + (kkquad ^ (sw4(d)<<1)), rowp = d^((d>>5)&1)
        u32x2* vw2 = (u32x2*)lds_v[buf];
        #pragma unroll
        for (int j = 0; j < 4; ++j) {
            const int d = vc * 4 + j;
            const int rowp = d ^ ((d >> 5) & 1);
            const int sx = sw4(d) << 1;
            u32x2 p0, p1;
            p0[0] = pkrtz(((const float*)&vr[0])[j], ((const float*)&vr[1])[j]);
            p0[1] = pkrtz(((const float*)&vr[2])[j], ((const float*)&vr[3])[j]);
            p1[0] = pkrtz(((const float*)&vr[4])[j], ((const float*)&vr[5])[j]);
            p1[1] = pkrtz(((const float*)&vr[6])[j], ((const float*)&vr[7])[j]);
            vw2[rowp * 8 + ((2 * v4)     ^ sx)] = p0;   // kk 8v4..8v4+3
            vw2[rowp * 8 + ((2 * v4 + 1) ^ sx)] = p1;   // kk 8v4+4..8v4+7
        }
    };

    // ================= consumer state =================
    // Q^T as B-operand: lane holds Q[q = q0+wv*32+l31][d = c*16 + h*8 + j],
    // pre-scaled by log2(e) so softmax runs in exp2 domain.
    f16x8 qf[8];
    if (!producer) {
        const float* qp = qg + (size_t)(b * Nn + q0 + wv * 32 + l31) * Dd + h * 8;
        #pragma unroll
        for (int c = 0; c < 8; ++c) {
            float4 x0 = *(const float4*)(qp + c * 16);
            float4 x1 = *(const float4*)(qp + c * 16 + 4);
            const float xv[8] = {x0.x, x0.y, x0.z, x0.w, x1.x, x1.y, x1.z, x1.w};
            union { f16x8 v; _Float16 e[8]; } u;
            #pragma unroll
            for (int j = 0; j < 8; ++j)
                u.e[j] = (_Float16)(xv[j] * 1.44269504088896340736f);
            qf[c] = u.v;
        }
    }
    f32x16 accO[4];   // O^T[dout = dt*32 + C-row][q = l31]
    #pragma unroll
    for (int dt = 0; dt < 4; ++dt)
        #pragma unroll
        for (int r = 0; r < 16; ++r) accO[dt][r] = 0.f;
    float m_i = -1e30f, l_i = 0.f;   // per-lane (q = l31), log2 domain

    auto consume = [&](const ushort* kb, const ushort* vb) {
        // ---- S^T[kk=32][q=32] = K' x Q^T, K-dim 128 in 8 chunks ----
        f32x16 accS;
        #pragma unroll
        for (int r = 0; r < 16; ++r) accS[r] = 0.f;
        {
            const int sw = swz(l31) << 3;
            const int rx = (l31 & 8) << 2;
            __builtin_amdgcn_s_setprio(1);
            #pragma unroll
            for (int c = 0; c < 8; ++c) {
                f16x8 kf = *(const f16x8*)&kb[l31 * Dd + ((c * 16 + h * 8) ^ sw ^ rx)];
                accS = __builtin_amdgcn_mfma_f32_32x32x16_f16(kf, qf[c], accS, 0, 0, 0);
            }
            __builtin_amdgcn_s_setprio(0);
        }

        // ---- V fragments early (independent of softmax) ----
        f16x8 vf[4][2];
        #pragma unroll
        for (int dt = 0; dt < 4; ++dt) {
            const int drow = dt * 32 + l31;
            const int rowp = drow ^ ((drow >> 5) & 1);
            const int sv = sw4(drow) << 3;
            vf[dt][0] = *(const f16x8*)&vb[rowp * BN + ((8 * h) ^ sv)];
            vf[dt][1] = *(const f16x8*)&vb[rowp * BN + ((16 + 8 * h) ^ sv)];
        }

        // ---- online softmax (exp2 domain), per-lane row (q = l31) ----
        float t0 = fmaxf(accS[0], accS[1]),  t1 = fmaxf(accS[2], accS[3]);
        float t2 = fmaxf(accS[4], accS[5]),  t3 = fmaxf(accS[6], accS[7]);
        float t4 = fmaxf(accS[8], accS[9]),  t5 = fmaxf(accS[10], accS[11]);
        float t6 = fmaxf(accS[12], accS[13]), t7 = fmaxf(accS[14], accS[15]);
        float u0 = fmaxf(t0, t1), u1 = fmaxf(t2, t3);
        float u2 = fmaxf(t4, t5), u3 = fmaxf(t6, t7);
        float mx = fmaxf(fmaxf(u0, u1), fmaxf(u2, u3));
        mx = fmaxf(mx, __shfl_xor(mx, 32, 64));

        // defer-rescale: only pay alpha + 64-mul rescale when max grew >8
        if (!__all(mx <= m_i + 8.f)) {
            const float mn = fmaxf(m_i, mx);
            const float al = exp2i(m_i - mn);
            m_i = mn;
            l_i *= al;
            #pragma unroll
            for (int dt = 0; dt < 4; ++dt)
                #pragma unroll
                for (int r = 0; r < 16; ++r) accO[dt][r] *= al;
        }
        #pragma unroll
        for (int r = 0; r < 16; ++r) accS[r] = exp2i(accS[r] - m_i);
        {   // tree-sum (depth 4)
            float a0 = accS[0] + accS[1],   a1 = accS[2] + accS[3];
            float a2 = accS[4] + accS[5],   a3 = accS[6] + accS[7];
            float a4 = accS[8] + accS[9],   a5 = accS[10] + accS[11];
            float a6 = accS[12] + accS[13], a7 = accS[14] + accS[15];
            float b0 = a0 + a1, b1 = a2 + a3, b2 = a4 + a5, b3 = a6 + a7;
            l_i += (b0 + b1) + (b2 + b3);
        }

        // ---- P^T -> MFMA B-fragments entirely in registers ----
        // accS[r] at half h' holds P[kk=(r&3)+8*(r>>2)+4h'][q=l31].
        const uint pA0 = pkrtz(accS[0],  accS[1]);
        const uint pA1 = pkrtz(accS[2],  accS[3]);
        const uint pB0 = pkrtz(accS[4],  accS[5]);
        const uint pB1 = pkrtz(accS[6],  accS[7]);
        const uint pC0 = pkrtz(accS[8],  accS[9]);
        const uint pC1 = pkrtz(accS[10], accS[11]);
        const uint pD0 = pkrtz(accS[12], accS[13]);
        const uint pD1 = pkrtz(accS[14], accS[15]);
        const uint yA0 = __shfl_xor(pA0, 32, 64);
        const uint yA1 = __shfl_xor(pA1, 32, 64);
        const uint yB0 = __shfl_xor(pB0, 32, 64);
        const uint yB1 = __shfl_xor(pB1, 32, 64);
        const uint yC0 = __shfl_xor(pC0, 32, 64);
        const uint yC1 = __shfl_xor(pC1, 32, 64);
        const uint yD0 = __shfl_xor(pD0, 32, 64);
        const uint yD1 = __shfl_xor(pD1, 32, 64);
        union { uint u[4]; f16x8 v; } P0, P1;
        P0.u[0] = h ? yB0 : pA0;
        P0.u[1] = h ? yB1 : pA1;
        P0.u[2] = h ? pB0 : yA0;
        P0.u[3] = h ? pB1 : yA1;
        P1.u[0] = h ? yD0 : pC0;
        P1.u[1] = h ? yD1 : pC1;
        P1.u[2] = h ? pD0 : yC0;
        P1.u[3] = h ? pD1 : yC1;
        const f16x8 pf0 = P0.v, pf1 = P1.v;

        // ---- O^T += V' x P^T : 4 dout tiles x 2 kk-chunks ----
        __builtin_amdgcn_s_setprio(1);
        #pragma unroll
        for (int dt = 0; dt < 4; ++dt) {
            accO[dt] = __builtin_amdgcn_mfma_f32_32x32x16_f16(vf[dt][0], pf0, accO[dt], 0, 0, 0);
            accO[dt] = __builtin_amdgcn_mfma_f32_32x32x16_f16(vf[dt][1], pf1, accO[dt], 0, 0, 0);
        }
        __builtin_amdgcn_s_setprio(0);
    };

    // ================= pipeline =================
    // Producer (single reg set, write-then-reissue): at interval t, write
    // tile t+1 (loads issued at t-1, one interval to land), then issue
    // loads for tile t+2 into the same regs.
    if (producer) {
        issue_loads(0);      // tile 0
        write_lds(0);        // tile 0 -> buf0 (vmcnt wait by dependency)
        issue_loads(BN);     // tile 1, in flight across the barrier
    }
    __syncthreads();

    constexpr int ITERS = Nn / BN;   // 64
    for (int it = 0; it < ITERS; it += 2) {
        // even iter: write tile it+1 -> buf1, reissue it+2, consume buf0
        if (producer) {
            write_lds(1);
            if (it + 2 < ITERS) issue_loads((it + 2) * BN);
        } else {
            consume(lds_k[0], lds_v[0]);
        }
        __syncthreads();
        // odd iter: write tile it+2 -> buf0, reissue it+3, consume buf1
        if (producer) {
            if (it + 2 < ITERS) write_lds(0);
            if (it + 3 < ITERS) issue_loads((it + 3) * BN);
        } else {
            consume(lds_k[1], lds_v[1]);
        }
        __syncthreads();
    }

    // ================= epilogue (consumers) =================
    if (!producer) {
        float l = l_i + __shfl_xor(l_i, 32, 64);
        const float inv = 1.f / l;
        float* ob = og + (size_t)(b * Nn + q0 + wv * 32 + l31) * Dd;
        #pragma unroll
        for (int dt = 0; dt < 4; ++dt) {
            #pragma unroll
            for (int g = 0; g < 4; ++g) {
                float4 val;
                val.x = accO[dt][4 * g + 0] * inv;
                val.y = accO[dt][4 * g + 1] * inv;
                val.z = accO[dt][4 * g + 2] * inv;
                val.w = accO[dt][4 * g + 3] * inv;
                *(float4*)(ob + dt * 32 + 8 * g + 4 * h) = val;
            }
        }
    }
}

extern "C" void kernel_launch(void* const* d_in, const int* in_sizes, int n_in,
                              void* d_out, int out_size, void* d_ws, size_t ws_size,
                              hipStream_t stream) {
    const float* q = (const float*)d_in[0];
    const float* k = (const float*)d_in[1];
    const float* v = (const float*)d_in[2];
    float* o = (float*)d_out;
    (void)d_ws; (void)ws_size; (void)in_sizes; (void)n_in; (void)out_size;
    fattn_kernel<<<dim3(Bz * (Nn / BM)), dim3(256), 0, stream>>>(q, k, v, o);
}

// Round 15
// 147.777 us; speedup vs baseline: 1.0632x; 1.0632x over previous
//
#include <hip/hip_runtime.h>

// Flash attention fwd. q[B,N,D], k[B,D,N] (=K^T), v[B,N,D] fp32 in, fp32 out.
// B=16, N=2048, D=128. fp16 MFMA (32x32x16), fp32 accumulate.
// R21 (two-pass: pre-swizzled f16 K/V images + DMA-staged all-consumer):
//  - Pass 1 (build_images): K/V converted to f16 and laid out in d_ws as
//    8KB tile images that are BYTE-EXACT LDS contents (R19's swizzled
//    layout baked in). DMA can't swizzle (m104); pre-swizzling the
//    source (m173) makes LDS-side linear.
//  - Pass 2: R14's all-consumer split-KV skeleton (8 waves: grp 0 keys
//    0..1023, grp 1 keys 1024..2047, same 128 q-rows; fp32 merge at end
//    -- R14's merge passed refcheck). Staging = 4 global_load_lds per
//    thread (async DMA): no staging regs, no ds_writes, no pkrtz on the
//    wave critical path -- removes exactly what made R14 lose to R9.
//    DMA(t+1) issues before consume(t); __syncthreads' vmcnt(0) drain is
//    the completion wait and is nearly free (loads had ~1100cy to land).
//  - f16 halves stream bytes; per-XCD K/V working set 4MB -> 2MB (fits L2).
//  - Consumer body = R19/R20 (exp2 softmax, defer-rescale THR=8,
//    tree-sum, P^T in regs via shfl_xor, setprio).

typedef __attribute__((ext_vector_type(8))) _Float16 f16x8;
typedef __attribute__((ext_vector_type(16))) float f32x16;

constexpr int Bz = 16;
constexpr int Nn = 2048;
constexpr int Dd = 128;
constexpr int BM = 128;  // q rows per block (4 waves x 32, shared by both groups)
constexpr int BN = 32;   // keys per tile
constexpr int NT = Nn / BN;          // 64 tiles per batch
constexpr int ITG = NT / 2;          // 32 tiles per group

__device__ __forceinline__ int swz(int r) { return (r ^ (r >> 3)) & 7; }
__device__ __forceinline__ int sw4(int d) { return ((d >> 1) ^ (d >> 3)) & 3; }

__device__ __forceinline__ uint pkrtz(float a, float b) {
    return __builtin_bit_cast(uint, __builtin_amdgcn_cvt_pkrtz(a, b));
}

__device__ __forceinline__ float exp2i(float x) {
    return __builtin_amdgcn_exp2f(x);   // raw v_exp_f32 (2^x)
}

// ================= pass 1: build pre-swizzled f16 tile images =================
// K image (8KB per tile, uint2 view, 1024 entries):
//   idx = n*32 + (dquad ^ (swz(n)<<1) ^ (n&8));  val = {pk(K[4dq],K[4dq+1]),
//   pk(K[4dq+2],K[4dq+3])} at column n.   (== R19 lds_k contents)
// V image (8KB per tile, uint2 view, 1024 entries):
//   idx = rowp*8 + (kkquad ^ (sw4(d)<<1)); rowp = d ^ ((d>>5)&1);
//   val = {pk(V[4kq][d],V[4kq+1][d]), pk(V[4kq+2][d],V[4kq+3][d])}.
__global__ __launch_bounds__(256)
void build_images(const float* __restrict__ kg, const float* __restrict__ vg,
                  uint* __restrict__ kimg, uint* __restrict__ vimg)
{
    __shared__ float sk[32][129];   // [n][d] (+1 pad: conflict-free col writes)
    __shared__ float sv[32][129];   // [kk][d]
    const int bid = blockIdx.x;     // b*64 + tile
    const int b   = bid >> 6;
    const int tt  = bid & 63;
    const int n0  = tt * 32;
    const int t   = threadIdx.x;

    const float* kb = kg + (size_t)b * Dd * Nn;
    #pragma unroll
    for (int i = 0; i < 16; ++i) {
        const int d = i * 8 + (t >> 5);
        const int n = t & 31;
        sk[n][d] = kb[(size_t)d * Nn + n0 + n];
    }
    const float* vb = vg + (size_t)b * Nn * Dd;
    #pragma unroll
    for (int i = 0; i < 16; ++i) {
        const int kk = i * 2 + (t >> 7);
        const int d  = t & 127;
        sv[kk][d] = vb[(size_t)(n0 + kk) * Dd + d];
    }
    __syncthreads();

    uint2* ko = (uint2*)(kimg + (size_t)bid * 2048);
    #pragma unroll
    for (int j = 0; j < 4; ++j) {
        const int I = t * 4 + j;
        const int n = I >> 5, m = I & 31;
        const int dq = m ^ ((swz(n) << 1) ^ (n & 8));
        const int d0 = dq * 4;
        uint2 pv;
        pv.x = pkrtz(sk[n][d0],     sk[n][d0 + 1]);
        pv.y = pkrtz(sk[n][d0 + 2], sk[n][d0 + 3]);
        ko[I] = pv;
    }
    uint2* vo = (uint2*)(vimg + (size_t)bid * 2048);
    #pragma unroll
    for (int j = 0; j < 4; ++j) {
        const int I = t * 4 + j;
        const int rowp = I >> 3, mm = I & 7;
        const int d  = rowp ^ ((rowp >> 5) & 1);   // involution
        const int kq = mm ^ (sw4(d) << 1);
        const int k0 = kq * 4;
        uint2 pv;
        pv.x = pkrtz(sv[k0][d],     sv[k0 + 1][d]);
        pv.y = pkrtz(sv[k0 + 2][d], sv[k0 + 3][d]);
        vo[I] = pv;
    }
}

// ================= pass 2: attention =================
typedef __attribute__((address_space(3))) uint lds_u32;

__global__ __launch_bounds__(512, 2)
void fattn_kernel(const float* __restrict__ qg,
                  const uint* __restrict__ kimg,
                  const uint* __restrict__ vimg,
                  float* __restrict__ og)
{
    __shared__ ushort lds_k[2][2][BN * Dd];  // [grp][buf]  4 x 8 KB
    __shared__ ushort lds_v[2][2][Dd * BN];  // [grp][buf]  4 x 8 KB
    __shared__ float  mlx[4][2][32];         // grp1 {m,l} per wave-pair

    const int bid  = blockIdx.x;           // 256 blocks
    const int xcd  = bid & 7;
    const int idx  = bid >> 3;             // 0..31
    const int b    = xcd * 2 + (idx >> 4);
    const int q0   = (idx & 15) * BM;
    const int tid  = threadIdx.x;
    const int wv   = tid >> 6;             // 0..7
    const int lane = tid & 63;
    const int h    = lane >> 5;            // half-wave (k-slice)
    const int l31  = lane & 31;
    const int grp  = wv >> 2;              // 0: keys 0..1023, 1: 1024..2047
    const int wq   = wv & 3;               // wave within group

    // ---- DMA staging: 2 K + 2 V global_load_lds per thread ----
    auto dma_tile = [&](int timg, int buf) {
        const uint* ksrc = kimg + (size_t)timg * 2048;
        const uint* vsrc = vimg + (size_t)timg * 2048;
        uint* kdst = (uint*)lds_k[grp][buf];
        uint* vdst = (uint*)lds_v[grp][buf];
        #pragma unroll
        for (int r = 0; r < 2; ++r) {
            const int off = (wq * 2 + r) * 256;   // 1KB slices, uniform per wave
            __builtin_amdgcn_global_load_lds(ksrc + off + lane * 4,
                                             (lds_u32*)(kdst + off), 16, 0, 0);
            __builtin_amdgcn_global_load_lds(vsrc + off + lane * 4,
                                             (lds_u32*)(vdst + off), 16, 0, 0);
        }
    };

    // Q^T as B-operand: lane holds Q[q = q0+wq*32+l31][d = c*16 + h*8 + j],
    // pre-scaled by log2(e). Both groups load the same rows (L2 hit).
    f16x8 qf[8];
    {
        const float* qp = qg + (size_t)(b * Nn + q0 + wq * 32 + l31) * Dd + h * 8;
        #pragma unroll
        for (int c = 0; c < 8; ++c) {
            float4 x0 = *(const float4*)(qp + c * 16);
            float4 x1 = *(const float4*)(qp + c * 16 + 4);
            const float xv[8] = {x0.x, x0.y, x0.z, x0.w, x1.x, x1.y, x1.z, x1.w};
            union { f16x8 v; _Float16 e[8]; } u;
            #pragma unroll
            for (int j = 0; j < 8; ++j)
                u.e[j] = (_Float16)(xv[j] * 1.44269504088896340736f);
            qf[c] = u.v;
        }
    }
    f32x16 accO[4];   // O^T[dout = dt*32 + C-row][q = l31] (group-partial)
    #pragma unroll
    for (int dt = 0; dt < 4; ++dt)
        #pragma unroll
        for (int r = 0; r < 16; ++r) accO[dt][r] = 0.f;
    float m_i = -1e30f, l_i = 0.f;   // per-lane, log2 domain (group-partial)

    auto consume = [&](const ushort* kb, const ushort* vb) {
        // ---- S^T[kk=32][q=32] = K' x Q^T ----
        f32x16 accS;
        #pragma unroll
        for (int r = 0; r < 16; ++r) accS[r] = 0.f;
        {
            const int sw = swz(l31) << 3;
            const int rx = (l31 & 8) << 2;
            __builtin_amdgcn_s_setprio(1);
            #pragma unroll
            for (int c = 0; c < 8; ++c) {
                f16x8 kf = *(const f16x8*)&kb[l31 * Dd + ((c * 16 + h * 8) ^ sw ^ rx)];
                accS = __builtin_amdgcn_mfma_f32_32x32x16_f16(kf, qf[c], accS, 0, 0, 0);
            }
            __builtin_amdgcn_s_setprio(0);
        }

        // ---- V fragments early (independent of softmax) ----
        f16x8 vf[4][2];
        #pragma unroll
        for (int dt = 0; dt < 4; ++dt) {
            const int drow = dt * 32 + l31;
            const int rowp = drow ^ ((drow >> 5) & 1);
            const int sv = sw4(drow) << 3;
            vf[dt][0] = *(const f16x8*)&vb[rowp * BN + ((8 * h) ^ sv)];
            vf[dt][1] = *(const f16x8*)&vb[rowp * BN + ((16 + 8 * h) ^ sv)];
        }

        // ---- online softmax (exp2 domain), per-lane row (q = l31) ----
        float t0 = fmaxf(accS[0], accS[1]),  t1 = fmaxf(accS[2], accS[3]);
        float t2 = fmaxf(accS[4], accS[5]),  t3 = fmaxf(accS[6], accS[7]);
        float t4 = fmaxf(accS[8], accS[9]),  t5 = fmaxf(accS[10], accS[11]);
        float t6 = fmaxf(accS[12], accS[13]), t7 = fmaxf(accS[14], accS[15]);
        float u0 = fmaxf(t0, t1), u1 = fmaxf(t2, t3);
        float u2 = fmaxf(t4, t5), u3 = fmaxf(t6, t7);
        float mx = fmaxf(fmaxf(u0, u1), fmaxf(u2, u3));
        mx = fmaxf(mx, __shfl_xor(mx, 32, 64));

        if (!__all(mx <= m_i + 8.f)) {
            const float mn = fmaxf(m_i, mx);
            const float al = exp2i(m_i - mn);
            m_i = mn;
            l_i *= al;
            #pragma unroll
            for (int dt = 0; dt < 4; ++dt)
                #pragma unroll
                for (int r = 0; r < 16; ++r) accO[dt][r] *= al;
        }
        #pragma unroll
        for (int r = 0; r < 16; ++r) accS[r] = exp2i(accS[r] - m_i);
        {   // tree-sum (depth 4)
            float a0 = accS[0] + accS[1],   a1 = accS[2] + accS[3];
            float a2 = accS[4] + accS[5],   a3 = accS[6] + accS[7];
            float a4 = accS[8] + accS[9],   a5 = accS[10] + accS[11];
            float a6 = accS[12] + accS[13], a7 = accS[14] + accS[15];
            float b0 = a0 + a1, b1 = a2 + a3, b2 = a4 + a5, b3 = a6 + a7;
            l_i += (b0 + b1) + (b2 + b3);
        }

        // ---- P^T -> MFMA B-fragments in registers ----
        const uint pA0 = pkrtz(accS[0],  accS[1]);
        const uint pA1 = pkrtz(accS[2],  accS[3]);
        const uint pB0 = pkrtz(accS[4],  accS[5]);
        const uint pB1 = pkrtz(accS[6],  accS[7]);
        const uint pC0 = pkrtz(accS[8],  accS[9]);
        const uint pC1 = pkrtz(accS[10], accS[11]);
        const uint pD0 = pkrtz(accS[12], accS[13]);
        const uint pD1 = pkrtz(accS[14], accS[15]);
        const uint yA0 = __shfl_xor(pA0, 32, 64);
        const uint yA1 = __shfl_xor(pA1, 32, 64);
        const uint yB0 = __shfl_xor(pB0, 32, 64);
        const uint yB1 = __shfl_xor(pB1, 32, 64);
        const uint yC0 = __shfl_xor(pC0, 32, 64);
        const uint yC1 = __shfl_xor(pC1, 32, 64);
        const uint yD0 = __shfl_xor(pD0, 32, 64);
        const uint yD1 = __shfl_xor(pD1, 32, 64);
        union { uint u[4]; f16x8 v; } P0, P1;
        P0.u[0] = h ? yB0 : pA0;
        P0.u[1] = h ? yB1 : pA1;
        P0.u[2] = h ? pB0 : yA0;
        P0.u[3] = h ? pB1 : yA1;
        P1.u[0] = h ? yD0 : pC0;
        P1.u[1] = h ? yD1 : pC1;
        P1.u[2] = h ? pD0 : yC0;
        P1.u[3] = h ? pD1 : yC1;
        const f16x8 pf0 = P0.v, pf1 = P1.v;

        __builtin_amdgcn_s_setprio(1);
        #pragma unroll
        for (int dt = 0; dt < 4; ++dt) {
            accO[dt] = __builtin_amdgcn_mfma_f32_32x32x16_f16(vf[dt][0], pf0, accO[dt], 0, 0, 0);
            accO[dt] = __builtin_amdgcn_mfma_f32_32x32x16_f16(vf[dt][1], pf1, accO[dt], 0, 0, 0);
        }
        __builtin_amdgcn_s_setprio(0);
    };

    // ================= pipeline (32 intervals per group) =================
    const int tbase = b * NT + grp * ITG;    // image tile index base
    dma_tile(tbase, 0);                      // tile 0 -> buf0
    __syncthreads();                         // drains vmcnt -> DMA complete

    for (int t = 0; t < ITG; ++t) {
        if (t + 1 < ITG) dma_tile(tbase + t + 1, (t + 1) & 1);  // async, lands under consume
        consume(lds_k[grp][t & 1], lds_v[grp][t & 1]);
        __syncthreads();                     // vmcnt drain = DMA(t+1) complete
    }

    // ================= merge groups (fp32, 2 rounds; R14-verified) =========
    float l_full = l_i + __shfl_xor(l_i, 32, 64);
    const int pair = wq;
    if (grp == 1 && h == 0) {
        mlx[pair][0][l31] = m_i;
        mlx[pair][1][l31] = l_full;
    }
    float* sc = (float*)lds_k;   // 32 KB scratch = 8192 floats = 2 pairs/round

    #pragma unroll
    for (int rnd = 0; rnd < 2; ++rnd) {
        if (grp == 1 && (pair >> 1) == rnd) {
            float* base = sc + (pair & 1) * 4096 + lane * 64;
            #pragma unroll
            for (int dt = 0; dt < 4; ++dt)
                #pragma unroll
                for (int r = 0; r < 16; ++r)
                    base[(dt * 16 + r) ^ l31] = accO[dt][r];
        }
        __syncthreads();
        if (grp == 0 && (pair >> 1) == rnd) {
            const float m_B = mlx[pair][0][l31];
            const float l_B = mlx[pair][1][l31];
            const float ms  = fmaxf(m_i, m_B);
            const float aA  = exp2i(m_i - ms);
            const float aB  = exp2i(m_B - ms);
            const float inv = 1.f / (aA * l_full + aB * l_B);
            const float* base = sc + (pair & 1) * 4096 + lane * 64;
            float* ob = og + (size_t)(b * Nn + q0 + wq * 32 + l31) * Dd;
            #pragma unroll
            for (int dt = 0; dt < 4; ++dt) {
                #pragma unroll
                for (int g = 0; g < 4; ++g) {
                    float4 val;
                    #pragma unroll
                    for (int j = 0; j < 4; ++j) {
                        const int r = 4 * g + j;
                        const float o = aA * accO[dt][r] + aB * base[(dt * 16 + r) ^ l31];
                        ((float*)&val)[j] = o * inv;
                    }
                    *(float4*)(ob + dt * 32 + 8 * g + 4 * h) = val;
                }
            }
        }
        __syncthreads();
    }
}

extern "C" void kernel_launch(void* const* d_in, const int* in_sizes, int n_in,
                              void* d_out, int out_size, void* d_ws, size_t ws_size,
                              hipStream_t stream) {
    const float* q = (const float*)d_in[0];
    const float* k = (const float*)d_in[1];
    const float* v = (const float*)d_in[2];
    float* o = (float*)d_out;
    (void)in_sizes; (void)n_in; (void)out_size; (void)ws_size;
    // workspace: K images (8MB) + V images (8MB) = 16MB of pre-swizzled f16
    uint* kimg = (uint*)d_ws;
    uint* vimg = kimg + (size_t)Bz * NT * 2048;
    build_images<<<dim3(Bz * NT), dim3(256), 0, stream>>>(k, v, kimg, vimg);
    fattn_kernel<<<dim3(Bz * (Nn / BM)), dim3(512), 0, stream>>>(q, kimg, vimg, o);
}